// Round 3
// baseline (226.655 us; speedup 1.0000x reference)
//
#include <hip/hip_runtime.h>

// reconstruction_loss: charbonnier_mean(get_msfa(X,4), get_msfa(Y,4))
// X, Y: [B=8, C=16, H=512, W=512] fp32. Pixel (b,h,w) uses channel
// c = (h%4)*4 + (w%4). Loss = mean over B*H*W of sqrt(d^2 + 1e-6).
//
// Work decomposition: plane c=4g+j contributes element j of every float4
// in rows h == g (mod 4). One work item per (b,g,j,r,k):
//   h = 4r+g, float4 index k in the row. Thread loads float4 from X and Y
//   (same offset), keeps lane j -> exactly one pixel's charbonnier term.
// Low bits of tid = k -> wave reads 64 consecutive float4s (1 KiB stream)
// per plane: ideal global_load_dwordx4 coalescing. j is wave-uniform
// (bits 14-15). Grid-stride advances b only (base + b*1MiB).
//
// HBM floor: every 64B line of used rows is touched (stride-16B elements)
// -> 4x overfetch is structural: 2 arrays * 32 MiB = 64 MiB.

#define EPS_F 1e-6f

constexpr int kBlocks  = 1024;
constexpr int kThreads = 256;
constexpr int kNPix    = 8 * 512 * 512;            // 2097152 items (one per pixel)
constexpr int kBatchF4 = 16 * 512 * 128;           // float4s per batch = 1<<20

__global__ __launch_bounds__(kThreads) void msfa_charb_partial(
    const float4* __restrict__ X4, const float4* __restrict__ Y4,
    float* __restrict__ partial)
{
    const int tid = blockIdx.x * kThreads + threadIdx.x;   // [0, 2^18)
    const int k = tid & 127;          // float4 index within row
    const int r = (tid >> 7) & 127;   // row-within-group
    const int j = (tid >> 14) & 3;    // element to keep (wave-uniform)
    const int g = tid >> 16;          // h-group, 0..3
    const int h = (r << 2) | g;       // h % 4 == g
    const int c = (g << 2) | j;       // channel plane
    const int base = (((c << 9) | h) << 7) | k;            // float4 offset in batch 0

    float acc = 0.0f;
#pragma unroll
    for (int b = 0; b < 8; ++b) {
        const int f = base + b * kBatchF4;
        const float4 x = X4[f];
        const float4 y = Y4[f];
        const float xv = (j == 0) ? x.x : (j == 1) ? x.y : (j == 2) ? x.z : x.w;
        const float yv = (j == 0) ? y.x : (j == 1) ? y.y : (j == 2) ? y.z : y.w;
        const float d = xv - yv;
        acc += sqrtf(d * d + EPS_F);
    }

    // wave64 butterfly reduce
#pragma unroll
    for (int s = 32; s > 0; s >>= 1)
        acc += __shfl_down(acc, s, 64);

    __shared__ float sdata[kThreads / 64];
    const int lane = threadIdx.x & 63;
    const int wave = threadIdx.x >> 6;
    if (lane == 0) sdata[wave] = acc;
    __syncthreads();
    if (threadIdx.x == 0) {
        float t = 0.0f;
#pragma unroll
        for (int i = 0; i < kThreads / 64; ++i) t += sdata[i];
        partial[blockIdx.x] = t;
    }
}

__global__ __launch_bounds__(1024) void msfa_finalize(
    const float* __restrict__ partial, float* __restrict__ out)
{
    float v = partial[threadIdx.x];              // 1024 partials, 1024 threads
#pragma unroll
    for (int s = 32; s > 0; s >>= 1)
        v += __shfl_down(v, s, 64);

    __shared__ float sdata[16];
    const int lane = threadIdx.x & 63;
    const int wave = threadIdx.x >> 6;
    if (lane == 0) sdata[wave] = v;
    __syncthreads();
    if (threadIdx.x == 0) {
        float t = 0.0f;
#pragma unroll
        for (int i = 0; i < 16; ++i) t += sdata[i];
        out[0] = t * (1.0f / (float)kNPix);
    }
}

extern "C" void kernel_launch(void* const* d_in, const int* in_sizes, int n_in,
                              void* d_out, int out_size, void* d_ws, size_t ws_size,
                              hipStream_t stream)
{
    const float4* X4 = (const float4*)d_in[0];
    const float4* Y4 = (const float4*)d_in[1];
    float* partial = (float*)d_ws;               // kBlocks floats = 4 KiB scratch
    float* out     = (float*)d_out;

    msfa_charb_partial<<<kBlocks, kThreads, 0, stream>>>(X4, Y4, partial);
    msfa_finalize<<<1, 1024, 0, stream>>>(partial, out);
}